// Round 10
// baseline (1995.577 us; speedup 1.0000x reference)
//
#include <hip/hip_runtime.h>
#include <hip/hip_bf16.h>

// RSmatching: masked-gather GRU + 2-class softmax head.
// v9 = v5 structure with the LLC round-trip chain halved:
//  - H exchange dwords: (tag<<16)|bf16(h). Gate threads publish ONE one-way
//    sc0 sc1 dword store each (no vmcnt ack, no flag store, no extra barrier).
//  - poll+stage merged: waves 4-5 (idle in v5) pull 48 contiguous dwords/lane
//    (12 dwordx4 in flight, one vmcnt), check 48 embedded tags, retry batch.
//    Successful probe IS the staged data -> pack bf16 -> swizzled LDS.
//  - parity double buffer + step tags: writer of h^{k+2} (tag k+3) into
//    parity k&1 requires it staged k+1, which requires all published k+1,
//    which requires all finished step k => no reader still needs h^k. Same
//    certification as v5, now self-carried by the data.
//  - 2 barriers/step. xg on the CACHED path (v8 lesson). gemm_xg separate.
//  - watchdog on the poll (2^16 batches) => guaranteed termination.

#define NB 64
#define NS 512
#define ND 768
#define TD 2304
#define NM 24
#define HXE 49152   // dwords per parity (64*768)

typedef __attribute__((ext_vector_type(4))) float f32x4;
typedef __attribute__((ext_vector_type(8))) short bf16x8;
typedef __attribute__((ext_vector_type(4))) unsigned int u32x4;

__device__ inline unsigned short f2bf(float f) {
  union { float f; unsigned u; } a; a.f = f;
  unsigned r = a.u + 0x7fff + ((a.u >> 16) & 1);
  return (unsigned short)(r >> 16);
}
__device__ inline float bf2f(unsigned short s) {
  union { unsigned u; float f; } a; a.u = ((unsigned)s) << 16;
  return a.f;
}

// ---- device-scope (LLC-served) helpers ----
__device__ inline void store_tag(unsigned* p, unsigned v) {
  asm volatile("global_store_dword %0, %1, off sc0 sc1"
               :: "v"(p), "v"(v) : "memory");
}
// 12 dwordx4 in flight, single vmcnt: one LLC RT for 48 dwords.
__device__ inline void load48_tag(const unsigned* p,
    u32x4& q0, u32x4& q1, u32x4& q2, u32x4& q3, u32x4& q4, u32x4& q5,
    u32x4& q6, u32x4& q7, u32x4& q8, u32x4& q9, u32x4& qa, u32x4& qb) {
  asm volatile(
      "global_load_dwordx4 %0, %12, off sc0 sc1\n\t"
      "global_load_dwordx4 %1, %12, off offset:16 sc0 sc1\n\t"
      "global_load_dwordx4 %2, %12, off offset:32 sc0 sc1\n\t"
      "global_load_dwordx4 %3, %12, off offset:48 sc0 sc1\n\t"
      "global_load_dwordx4 %4, %12, off offset:64 sc0 sc1\n\t"
      "global_load_dwordx4 %5, %12, off offset:80 sc0 sc1\n\t"
      "global_load_dwordx4 %6, %12, off offset:96 sc0 sc1\n\t"
      "global_load_dwordx4 %7, %12, off offset:112 sc0 sc1\n\t"
      "global_load_dwordx4 %8, %12, off offset:128 sc0 sc1\n\t"
      "global_load_dwordx4 %9, %12, off offset:144 sc0 sc1\n\t"
      "global_load_dwordx4 %10, %12, off offset:160 sc0 sc1\n\t"
      "global_load_dwordx4 %11, %12, off offset:176 sc0 sc1\n\t"
      "s_waitcnt vmcnt(0)"
      : "=&v"(q0), "=&v"(q1), "=&v"(q2), "=&v"(q3), "=&v"(q4), "=&v"(q5),
        "=&v"(q6), "=&v"(q7), "=&v"(q8), "=&v"(q9), "=&v"(qa), "=&v"(qb)
      : "v"(p) : "memory");
}
__device__ inline unsigned pk(unsigned a, unsigned b) {
  return (a & 0xffffu) | (b << 16);
}
__device__ inline unsigned mn4(u32x4 q) {
  unsigned m = q[0] >> 16;
  m = min(m, q[1] >> 16); m = min(m, q[2] >> 16); m = min(m, q[3] >> 16);
  return m;
}

// ---------------- fp32 -> bf16 ----------------
__global__ void cvt_f32_bf16(const float* __restrict__ in,
                             unsigned short* __restrict__ out, int n) {
  int i = (blockIdx.x * blockDim.x + threadIdx.x) * 4;
  int stride = gridDim.x * blockDim.x * 4;
  for (; i < n; i += stride) {
    float4 v = *(const float4*)(in + i);
    ushort4 o;
    o.x = f2bf(v.x); o.y = f2bf(v.y); o.z = f2bf(v.z); o.w = f2bf(v.w);
    *(ushort4*)(out + i) = o;
  }
}

// ---------------- compact selected positions ----------------
// ctrl[0..63]=cnt, ctrl[64]=cntmax
__global__ void compact_pos(const int* __restrict__ sot,
                            int* __restrict__ pos, int* __restrict__ ctrl) {
  int b = blockIdx.x, t = threadIdx.x;          // 512 threads
  int m = (sot[b * NS + t] != 0) ? 1 : 0;
  unsigned long long ball = __ballot(m);
  int wid = t >> 6, lane = t & 63;
  __shared__ int wcnt[8];
  int prefix = __popcll(ball & ((1ull << lane) - 1ull));
  if (lane == 63) wcnt[wid] = __popcll(ball);
  __syncthreads();
  int base = 0;
  for (int w = 0; w < wid; ++w) base += wcnt[w];
  if (m) pos[b * NS + base + prefix] = t;
  if (t == 511) {
    int total = base + wcnt[7];
    ctrl[b] = total;
    atomicMax(&ctrl[64], total);
  }
}

// ---------------- xg GEMM: gathered rows -> x-projection ----------------
#define BM 128
#define BN 256
__global__ __launch_bounds__(256) void gemm_xg(
    const float* __restrict__ seq,           // fp32 [64][512][768]
    const int* __restrict__ pos,
    const int* __restrict__ ctrl,
    const unsigned short* __restrict__ Bg,   // W_ih bf16 [2304][768]
    const float* __restrict__ bias,          // b_ih fp32
    unsigned short* __restrict__ C) {        // xg bf16 [32768][2304]
  const int cntmax = ctrl[64];
  const int m0 = blockIdx.x * BM;
  if (m0 >= cntmax * 64) return;
  const int n0 = blockIdx.y * BN;
  __shared__ unsigned short lA[BM * 64];
  __shared__ unsigned short lB[BN * 64];
  const int tid = threadIdx.x;
  const int wid = tid >> 6, lane = tid & 63;
  const int wm = (wid & 1) * 64, wn = (wid >> 1) * 128;

  f32x4 acc[4][8];
#pragma unroll
  for (int i = 0; i < 4; ++i)
#pragma unroll
    for (int j = 0; j < 8; ++j) { f32x4 z = {0.f,0.f,0.f,0.f}; acc[i][j] = z; }

  for (int kt = 0; kt < 12; ++kt) {          // K = 768 = 12*64
    __syncthreads();
#pragma unroll
    for (int c = 0; c < 4; ++c) {
      int idx = c * 256 + tid;
      int r = idx >> 3, ch = idx & 7;
      int gm = m0 + r, ks = gm >> 6, ss = gm & 63;
      float4 v0 = {0,0,0,0}, v1 = {0,0,0,0};
      if (ks < ctrl[ss]) {
        int t = pos[ss * NS + ks];
        const float* src = seq + ((size_t)ss * NS + t) * ND + kt * 64 + ch * 8;
        v0 = *(const float4*)src;
        v1 = *(const float4*)(src + 4);
      }
      uint4 o;
      o.x = f2bf(v0.x) | ((unsigned)f2bf(v0.y) << 16);
      o.y = f2bf(v0.z) | ((unsigned)f2bf(v0.w) << 16);
      o.z = f2bf(v1.x) | ((unsigned)f2bf(v1.y) << 16);
      o.w = f2bf(v1.z) | ((unsigned)f2bf(v1.w) << 16);
      *(uint4*)((char*)lA + r * 128 + ((ch * 16) ^ ((r & 7) << 4))) = o;
    }
#pragma unroll
    for (int c = 0; c < 8; ++c) {
      int idx = c * 256 + tid;
      int r = idx >> 3, ch = idx & 7;
      uint4 v = *(const uint4*)(Bg + (size_t)(n0 + r) * ND + kt * 64 + ch * 8);
      *(uint4*)((char*)lB + r * 128 + ((ch * 16) ^ ((r & 7) << 4))) = v;
    }
    __syncthreads();
#pragma unroll
    for (int kk = 0; kk < 2; ++kk) {
      bf16x8 af[4], bfr[8];
      int kb = kk * 64 + (lane >> 4) * 16;
#pragma unroll
      for (int i = 0; i < 4; ++i) {
        int rowA = wm + i * 16 + (lane & 15);
        af[i] = *(const bf16x8*)((const char*)lA + rowA * 128 + (kb ^ ((rowA & 7) << 4)));
      }
#pragma unroll
      for (int i = 0; i < 8; ++i) {
        int rowB = wn + i * 16 + (lane & 15);
        bfr[i] = *(const bf16x8*)((const char*)lB + rowB * 128 + (kb ^ ((rowB & 7) << 4)));
      }
#pragma unroll
      for (int mi = 0; mi < 4; ++mi)
#pragma unroll
        for (int ni = 0; ni < 8; ++ni)
          acc[mi][ni] = __builtin_amdgcn_mfma_f32_16x16x32_bf16(
              af[mi], bfr[ni], acc[mi][ni], 0, 0, 0);
    }
  }
#pragma unroll
  for (int mi = 0; mi < 4; ++mi)
#pragma unroll
    for (int ni = 0; ni < 8; ++ni) {
      int col = n0 + wn + ni * 16 + (lane & 15);
      float bv = bias[col];
#pragma unroll
      for (int j = 0; j < 4; ++j) {
        int row = m0 + wm + mi * 16 + (lane >> 4) * 4 + j;
        C[(size_t)row * TD + col] = f2bf(acc[mi][ni][j] + bv);
      }
    }
}

// ---------------- gang RNN (tag-in-data, bulk wave 4-5 poll-stage) --------
__global__ __launch_bounds__(384) void rnn_gang(
    const unsigned short* __restrict__ xg,     // bf16 [512*64][2304] (cached)
    const unsigned short* __restrict__ whhb,   // bf16 [2304][768]
    const float* __restrict__ bhh,
    const int* __restrict__ ctrl,
    unsigned* __restrict__ Hx,                 // [2][64][768] (tag<<16|bf16)
    const float* __restrict__ wcls,            // fp32 [2][768]
    float* __restrict__ partial) {             // fp32 [24][64][2]
  const int g  = blockIdx.x & 7;               // gang
  const int m  = blockIdx.x >> 3;              // member 0..23
  const int d0 = m * 32;
  const int t  = threadIdx.x;
  const int w  = t >> 6;
  const int lane = t & 63;
  const int c  = lane & 15;
  const int kg = lane >> 4;

  __shared__ __align__(16) char Hl[8 * 1536];            // 12 KB, swizzled
  __shared__ __align__(16) float hp[8][100];             // padded stride

  // my wave's M-tile W fragments -> registers (96 VGPR)
  const int lr = w * 16 + c;                   // local gate row 0..95
  const int grow = (lr >> 5) * ND + d0 + (lr & 31);
  bf16x8 afr[24];
#pragma unroll
  for (int kt = 0; kt < 24; ++kt)
    afr[kt] = *(const bf16x8*)(whhb + (size_t)grow * ND + kt * 32 + kg * 8);

  const int s  = (t >> 5) & 7;                 // gate-thread sample (t<256)
  const int d  = t & 31;                       // gate-thread dim
  const int sg = g * 8 + s;
  float br = 0.f, bz = 0.f, bn = 0.f, h = 0.f;
  int cnt_s = 0;
  if (t < 256) {
    br = bhh[d0 + d]; bz = bhh[ND + d0 + d]; bn = bhh[2 * ND + d0 + d];
    cnt_s = ctrl[sg];
  }
  int Kg = 0;
  for (int i = 0; i < 8; ++i) Kg = max(Kg, ctrl[g * 8 + i]);

  // publish address for my h dword
  unsigned* mypub = Hx + (size_t)sg * ND + d0 + d;       // + parity*HXE

  // stage geometry (waves 4-5): lane tid2 pulls 48 contiguous dwords
  const int tid2 = t - 256;                    // 0..127 for waves 4,5
  const unsigned* sbase = Hx + (size_t)g * 8 * ND + tid2 * 48;  // + parity
  const int sr   = tid2 >> 4;                  // sample row 0..7
  char* lbase = Hl + sr * 1536;
  const int boff = (tid2 & 15) * 96;           // byte base of 6 chunks
  const int swz  = (sr & 7) << 4;

  // init: publish h^0 = 0 with tag 1 into parity 0 (one-way)
  if (t < 256) store_tag(mypub, 1u << 16);

  // xg prologue (k=0, cached loads)
  float xr = 0.f, xz = 0.f, xn = 0.f;
  if (t < 256) {
    const unsigned short* xrow = xg + (size_t)sg * TD + d0 + d;
    xr = bf2f(xrow[0]); xz = bf2f(xrow[ND]); xn = bf2f(xrow[2 * ND]);
  }

  for (int k = 0; k < Kg; ++k) {
    // ---- poll-stage (waves 4-5): batch-load 48 dwords, tags gate freshness
    if (t >= 256) {
      const unsigned tk = (unsigned)(k + 1);
      const unsigned* src = sbase + (size_t)(k & 1) * HXE;
      u32x4 q0, q1, q2, q3, q4, q5, q6, q7, q8, q9, qa, qb;
      int spins = 0;
      for (;;) {
        load48_tag(src, q0, q1, q2, q3, q4, q5, q6, q7, q8, q9, qa, qb);
        unsigned mn = mn4(q0);
        mn = min(mn, mn4(q1)); mn = min(mn, mn4(q2)); mn = min(mn, mn4(q3));
        mn = min(mn, mn4(q4)); mn = min(mn, mn4(q5)); mn = min(mn, mn4(q6));
        mn = min(mn, mn4(q7)); mn = min(mn, mn4(q8)); mn = min(mn, mn4(q9));
        mn = min(mn, mn4(qa)); mn = min(mn, mn4(qb));
        if (__all(mn >= tk)) break;
        if (++spins > (1 << 16)) break;        // watchdog: proceed
      }
      u32x4 o0 = {pk(q0[0],q0[1]), pk(q0[2],q0[3]), pk(q1[0],q1[1]), pk(q1[2],q1[3])};
      u32x4 o1 = {pk(q2[0],q2[1]), pk(q2[2],q2[3]), pk(q3[0],q3[1]), pk(q3[2],q3[3])};
      u32x4 o2 = {pk(q4[0],q4[1]), pk(q4[2],q4[3]), pk(q5[0],q5[1]), pk(q5[2],q5[3])};
      u32x4 o3 = {pk(q6[0],q6[1]), pk(q6[2],q6[3]), pk(q7[0],q7[1]), pk(q7[2],q7[3])};
      u32x4 o4 = {pk(q8[0],q8[1]), pk(q8[2],q8[3]), pk(q9[0],q9[1]), pk(q9[2],q9[3])};
      u32x4 o5 = {pk(qa[0],qa[1]), pk(qa[2],qa[3]), pk(qb[0],qb[1]), pk(qb[2],qb[3])};
      *(u32x4*)(lbase + ((boff +  0) ^ swz)) = o0;
      *(u32x4*)(lbase + ((boff + 16) ^ swz)) = o1;
      *(u32x4*)(lbase + ((boff + 32) ^ swz)) = o2;
      *(u32x4*)(lbase + ((boff + 48) ^ swz)) = o3;
      *(u32x4*)(lbase + ((boff + 64) ^ swz)) = o4;
      *(u32x4*)(lbase + ((boff + 80) ^ swz)) = o5;
    }
    __syncthreads();                           // B1: Hl ready
    // ---- MFMA: hp[96 rows][8 samples] for my tile (all 6 waves)
    f32x4 acc = {0.f, 0.f, 0.f, 0.f};
#pragma unroll
    for (int kt = 0; kt < 24; ++kt) {
      bf16x8 bfr = *(const bf16x8*)(Hl + (c & 7) * 1536 +
                    ((kt * 64 + kg * 16) ^ ((c & 7) << 4)));
      acc = __builtin_amdgcn_mfma_f32_16x16x32_bf16(afr[kt], bfr, acc, 0, 0, 0);
    }
    if (c < 8) *(f32x4*)&hp[c][w * 16 + kg * 4] = acc;
    __syncthreads();                           // B2: hp ready
    // ---- gates (waves 0-3); publish one-way tagged dword; xg prefetch
    if (t < 256) {
      float ar = hp[s][d]      + br;
      float az = hp[s][32 + d] + bz;
      float an = hp[s][64 + d] + bn;
      float r  = 1.f / (1.f + __expf(-(xr + ar)));
      float z  = 1.f / (1.f + __expf(-(xz + az)));
      float nn = tanhf(xn + r * an);
      float hn = (1.f - z) * nn + z * h;
      if (k < cnt_s) h = hn;
      unsigned pv = (unsigned)f2bf(h) | ((unsigned)(k + 2) << 16);
      store_tag(mypub + (size_t)((k + 1) & 1) * HXE, pv);
      if (k + 1 < Kg) {                        // cached xg prefetch for k+1
        const unsigned short* xrow = xg + ((size_t)(k + 1) * 64 + sg) * TD + d0 + d;
        xr = bf2f(xrow[0]); xz = bf2f(xrow[ND]); xn = bf2f(xrow[2 * ND]);
      }
    }
    // waves 4-5 loop straight back to poll-stage of k+1 (overlaps gates)
  }

  // classifier partials over my 32 dims
  if (t < 256) {
    float p0 = h * wcls[d0 + d];
    float p1 = h * wcls[ND + d0 + d];
#pragma unroll
    for (int off = 16; off; off >>= 1) {
      p0 += __shfl_xor(p0, off);
      p1 += __shfl_xor(p1, off);
    }
    if (d == 0) {
      partial[(size_t)(m * 64 + sg) * 2]     = p0;
      partial[(size_t)(m * 64 + sg) * 2 + 1] = p1;
    }
  }
}

// ---------------- finalize: sum partials + softmax ----------------
__global__ void finalize(const float* __restrict__ partial,
                         const float* __restrict__ bcls,
                         float* __restrict__ out) {
  int s = threadIdx.x;                         // 64
  float l0 = bcls[0], l1 = bcls[1];
  for (int m = 0; m < NM; ++m) {
    l0 += partial[(size_t)(m * 64 + s) * 2];
    l1 += partial[(size_t)(m * 64 + s) * 2 + 1];
  }
  float mx = fmaxf(l0, l1);
  float e0 = __expf(l0 - mx), e1 = __expf(l1 - mx);
  float inv = 1.f / (e0 + e1);
  out[2 * s]     = e0 * inv;
  out[2 * s + 1] = e1 * inv;
}

extern "C" void kernel_launch(void* const* d_in, const int* in_sizes, int n_in,
                              void* d_out, int out_size, void* d_ws, size_t ws_size,
                              hipStream_t stream) {
  const float* seq  = (const float*)d_in[0];
  const int*   sot  = (const int*)d_in[1];
  const float* Wih  = (const float*)d_in[2];
  const float* Whh  = (const float*)d_in[3];
  const float* bih  = (const float*)d_in[4];
  const float* bhh  = (const float*)d_in[5];
  const float* Wcls = (const float*)d_in[6];
  const float* bcls = (const float*)d_in[7];
  float* out = (float*)d_out;

  char* ws = (char*)d_ws;
  unsigned short* xg   = (unsigned short*)(ws);                   // 150,994,944
  unsigned short* wihb = (unsigned short*)(ws + 150994944);       // +3,538,944
  unsigned short* whhb = (unsigned short*)(ws + 154533888);       // +3,538,944
  int*            pos  = (int*)(ws + 158072832);                  // +131,072
  int*            ctrl = (int*)(ws + 158203904);                  // +512
  unsigned*       Hx   = (unsigned*)(ws + 158204416);             // +393,216
  float*          part = (float*)(ws + 158597632);                // +12,288

  cvt_f32_bf16<<<1728, 256, 0, stream>>>(Wih, wihb, TD * ND);
  cvt_f32_bf16<<<1728, 256, 0, stream>>>(Whh, whhb, TD * ND);
  hipMemsetAsync(ctrl, 0, 512, stream);
  hipMemsetAsync(Hx, 0, 2 * HXE * 4, stream);     // reset tags (graph replay)
  compact_pos<<<NB, NS, 0, stream>>>(sot, pos, ctrl);
  gemm_xg<<<dim3(NB * NS / BM, TD / BN), 256, 0, stream>>>(seq, pos, ctrl, wihb, bih, xg);
  rnn_gang<<<192, 384, 0, stream>>>(xg, whhb, bhh, ctrl, Hx, Wcls, part);
  finalize<<<1, 64, 0, stream>>>(part, bcls, out);
}

// Round 11
// 1567.887 us; speedup vs baseline: 1.2728x; 1.2728x over previous
//
#include <hip/hip_runtime.h>
#include <hip/hip_bf16.h>

// RSmatching: masked-gather GRU + 2-class softmax head.
// v10 = v5's rnn protocol VERBATIM (wave-0 flag poll + bulk stage + gathered
//       publish, sc0 sc1 LLC ops, 4 barriers/step) + x-projection FUSED into
//       the step (kills gemm_xg + cvt kernels + xg buffer):
//  - member m holds 96 W_hh rows AND 96 W_ih rows as bf16 VGPR fragments
//    (converted from fp32 in the prologue; no cvt dispatches).
//  - per step: stage x(k+1) = seq[s][pos[s][k+1]] (8x768 fp32, cached loads)
//    into double-buffered swizzled LDS alongside the H stage; after the hp
//    barrier, 24 xp-MFMAs compute acc_x(k+1) in time previously idle.
//  - acc_x seeds the hp accumulator for r/z waves (xr+hr merged for free);
//    n waves keep xn separate (tanh(xn + r*hn)) via extra hp columns.
//  - protocol lesson bank (v6-v9): any poll-traffic amplification regresses;
//    only wave 0 polls, 24 dwords, everyone else barriers. UNCHANGED.

#define NB 64
#define NS 512
#define ND 768
#define NM 24
#define HXE 49152   // bf16 elems per parity of Hb (64*768)

typedef __attribute__((ext_vector_type(4))) float f32x4;
typedef __attribute__((ext_vector_type(8))) short bf16x8;
typedef __attribute__((ext_vector_type(4))) unsigned int u32x4;

__device__ inline unsigned short f2bf(float f) {
  union { float f; unsigned u; } a; a.f = f;
  unsigned r = a.u + 0x7fff + ((a.u >> 16) & 1);
  return (unsigned short)(r >> 16);
}
__device__ inline unsigned pk2(float a, float b) {
  return (unsigned)f2bf(a) | ((unsigned)f2bf(b) << 16);
}
__device__ inline bf16x8 pack8(float4 a, float4 b) {
  bf16x8 r;
  r[0] = (short)f2bf(a.x); r[1] = (short)f2bf(a.y);
  r[2] = (short)f2bf(a.z); r[3] = (short)f2bf(a.w);
  r[4] = (short)f2bf(b.x); r[5] = (short)f2bf(b.y);
  r[6] = (short)f2bf(b.z); r[7] = (short)f2bf(b.w);
  return r;
}

// ---- device-scope (LLC-served) helpers (v5 verbatim) ----
__device__ inline int load_flag(const int* p) {
  int v;
  asm volatile("global_load_dword %0, %1, off sc0 sc1\n\ts_waitcnt vmcnt(0)"
               : "=v"(v) : "v"(p) : "memory");
  return v;
}
__device__ inline void store_flag(int* p, int v) {
  asm volatile("global_store_dword %0, %1, off sc0 sc1"
               :: "v"(p), "v"(v) : "memory");
}
__device__ inline void store_h16(void* p, u32x4 v) {
  asm volatile("global_store_dwordx4 %0, %1, off sc0 sc1"
               :: "v"(p), "v"(v) : "memory");
}
__device__ inline void load2_h16(const void* p0, const void* p1,
                                 u32x4& a, u32x4& b) {
  asm volatile("global_load_dwordx4 %0, %2, off sc0 sc1\n\t"
               "global_load_dwordx4 %1, %3, off sc0 sc1\n\t"
               "s_waitcnt vmcnt(0)"
               : "=&v"(a), "=&v"(b) : "v"(p0), "v"(p1) : "memory");
}
__device__ inline void waitcnt_vm0() {
  asm volatile("s_waitcnt vmcnt(0)" ::: "memory");
}

// ---------------- compact selected positions ----------------
// ctrl[0..63]=cnt, ctrl[64]=cntmax
__global__ void compact_pos(const int* __restrict__ sot,
                            int* __restrict__ pos, int* __restrict__ ctrl) {
  int b = blockIdx.x, t = threadIdx.x;          // 512 threads
  int m = (sot[b * NS + t] != 0) ? 1 : 0;
  unsigned long long ball = __ballot(m);
  int wid = t >> 6, lane = t & 63;
  __shared__ int wcnt[8];
  int prefix = __popcll(ball & ((1ull << lane) - 1ull));
  if (lane == 63) wcnt[wid] = __popcll(ball);
  __syncthreads();
  int base = 0;
  for (int w = 0; w < wid; ++w) base += wcnt[w];
  if (m) pos[b * NS + base + prefix] = t;
  if (t == 511) {
    int total = base + wcnt[7];
    ctrl[b] = total;
    atomicMax(&ctrl[64], total);
  }
}

// ---------------- gang RNN with fused x-projection ----------------
__global__ __launch_bounds__(384) void rnn_gang(
    const float* __restrict__ seq,             // fp32 [64][512][768]
    const int* __restrict__ pos,
    const int* __restrict__ ctrl,
    const float* __restrict__ whh,             // fp32 [2304][768]
    const float* __restrict__ wih,             // fp32 [2304][768]
    const float* __restrict__ bhh,
    const float* __restrict__ bih,
    int* __restrict__ flags,                   // [8][24] x16 ints
    unsigned short* __restrict__ Hb,           // bf16 [2][64][768]
    const float* __restrict__ wcls,            // fp32 [2][768]
    float* __restrict__ partial) {             // fp32 [24][64][2]
  const int g  = blockIdx.x & 7;               // gang
  const int m  = blockIdx.x >> 3;              // member 0..23
  const int d0 = m * 32;
  const int t  = threadIdx.x;
  const int w  = t >> 6;
  const int lane = t & 63;
  const int c  = lane & 15;
  const int kg = lane >> 4;

  __shared__ __align__(16) char Hl[8 * 1536];            // 12 KB H, swizzled
  __shared__ __align__(16) char Xl[2 * 8 * 1536];        // 24 KB x, dbuf
  __shared__ __align__(16) float hp[8][136];             // 96 merged + 32 xn
  __shared__ __align__(16) unsigned short hstage[256];

  // W_hh + W_ih fragments -> registers (~192 VGPR), fp32->bf16 inline
  const int lr = w * 16 + c;                   // local gate row 0..95
  const int grow = (lr >> 5) * ND + d0 + (lr & 31);
  bf16x8 afr[24], air[24];
#pragma unroll
  for (int kt = 0; kt < 24; ++kt) {
    const float* s1 = whh + (size_t)grow * ND + kt * 32 + kg * 8;
    afr[kt] = pack8(*(const float4*)s1, *(const float4*)(s1 + 4));
    const float* s2 = wih + (size_t)grow * ND + kt * 32 + kg * 8;
    air[kt] = pack8(*(const float4*)s2, *(const float4*)(s2 + 4));
  }

  const int s  = (t >> 5) & 7;                 // gate-thread sample (t<256)
  const int d  = t & 31;                       // gate-thread dim
  const int sg = g * 8 + s;
  float b_r = 0.f, b_z = 0.f, b_in = 0.f, b_hn = 0.f, h = 0.f;
  int cnt_s = 0;
  if (t < 256) {
    b_r  = bih[d0 + d] + bhh[d0 + d];
    b_z  = bih[ND + d0 + d] + bhh[ND + d0 + d];
    b_in = bih[2 * ND + d0 + d];
    b_hn = bhh[2 * ND + d0 + d];
    cnt_s = ctrl[sg];
  }
  int Kg = 0;
  for (int i = 0; i < 8; ++i) Kg = max(Kg, ctrl[g * 8 + i]);
  int* FG = flags + g * NM * 16;
  const int pm = lane < NM ? lane : (lane < 2 * NM ? lane - NM : lane - 2 * NM);

  // x staging geometry: thread stages 16 cols of one sample row
  const int xrow = t / 48;                     // 0..7
  const int xcol = (t - xrow * 48) * 16;       // 0..752
  const int cnt_row = ctrl[g * 8 + xrow];
  const float* xsrc_base = seq + (size_t)(g * 8 + xrow) * NS * ND + xcol;
  const int* xpos_base = pos + (g * 8 + xrow) * NS;
  const int xswz = (xrow & 7) << 4;

  // zero both parities of my H slice, publish flag=1 (v5 verbatim)
  if (t < 32) {
    u32x4 z = {0u, 0u, 0u, 0u};
    store_h16(Hb + ((size_t)(g * 8 + (t >> 2))) * ND + d0 + (t & 3) * 8, z);
    store_h16(Hb + ((size_t)(64 + g * 8 + (t >> 2))) * ND + d0 + (t & 3) * 8, z);
  }
  waitcnt_vm0();
  __syncthreads();
  if (t == 0) store_flag(&FG[m * 16], 1);

  // prologue: stage x(0) -> Xl[0], compute acc_x(0)
  {
    int p = xpos_base[0];
    const float* src = xsrc_base + (size_t)p * ND;
    float4 v0 = *(const float4*)src,      v1 = *(const float4*)(src + 4);
    float4 v2 = *(const float4*)(src + 8), v3 = *(const float4*)(src + 12);
    uint4 o0, o1;
    o0.x = pk2(v0.x, v0.y); o0.y = pk2(v0.z, v0.w);
    o0.z = pk2(v1.x, v1.y); o0.w = pk2(v1.z, v1.w);
    o1.x = pk2(v2.x, v2.y); o1.y = pk2(v2.z, v2.w);
    o1.z = pk2(v3.x, v3.y); o1.w = pk2(v3.z, v3.w);
    char* xb = Xl + xrow * 1536;
    *(uint4*)(xb + ((xcol * 2) ^ xswz)) = o0;
    *(uint4*)(xb + ((xcol * 2 + 16) ^ xswz)) = o1;
  }
  __syncthreads();
  f32x4 acc_x = {0.f, 0.f, 0.f, 0.f};
#pragma unroll
  for (int kt = 0; kt < 24; ++kt) {
    bf16x8 bfr = *(const bf16x8*)(Xl + (c & 7) * 1536 +
                  ((kt * 64 + kg * 16) ^ ((c & 7) << 4)));
    acc_x = __builtin_amdgcn_mfma_f32_16x16x32_bf16(air[kt], bfr, acc_x, 0, 0, 0);
  }

  int dead = 0;
  for (int k = 0; k < Kg; ++k) {
    // (B) poll gang flags (v5 verbatim: wave 0 only, 24 dwords, watchdog)
    if (w == 0 && !dead) {
      const int* fp = &FG[pm * 16];
      const unsigned tk = (unsigned)(k + 1);
      int spins = 0;
      while (true) {
        int v = load_flag(fp);
        if (__all((unsigned)v >= tk)) break;
        if (++spins > (1 << 20)) { dead = 1; break; }
      }
    }
    __syncthreads();                           // B1
    // (C1) stage x(k+1) -> Xl[(k+1)&1] (plain cached loads, no sync dep)
    {
      int kk = (k + 1 < Kg) ? k + 1 : Kg - 1;
      int idx = (kk < cnt_row) ? kk : cnt_row - 1;
      int p = xpos_base[idx];
      const float* src = xsrc_base + (size_t)p * ND;
      float4 v0 = *(const float4*)src,      v1 = *(const float4*)(src + 4);
      float4 v2 = *(const float4*)(src + 8), v3 = *(const float4*)(src + 12);
      uint4 o0, o1;
      o0.x = pk2(v0.x, v0.y); o0.y = pk2(v0.z, v0.w);
      o0.z = pk2(v1.x, v1.y); o0.w = pk2(v1.z, v1.w);
      o1.x = pk2(v2.x, v2.y); o1.y = pk2(v2.z, v2.w);
      o1.z = pk2(v3.x, v3.y); o1.w = pk2(v3.z, v3.w);
      char* xb = Xl + ((k + 1) & 1) * 12288 + xrow * 1536;
      *(uint4*)(xb + ((xcol * 2) ^ xswz)) = o0;
      *(uint4*)(xb + ((xcol * 2 + 16) ^ xswz)) = o1;
    }
    // (C2) stage H(k) -> swizzled Hl (v5 verbatim)
    {
      const unsigned short* hsrc = Hb + ((size_t)(k & 1) * 64 + g * 8) * ND;
      int i1 = t + 384;
      int r0 = t / 96, c0 = t - r0 * 96;
      int r1 = i1 / 96, c1 = i1 - r1 * 96;
      u32x4 a0, a1;
      load2_h16(hsrc + r0 * ND + c0 * 8, hsrc + r1 * ND + c1 * 8, a0, a1);
      *(u32x4*)(Hl + r0 * 1536 + ((c0 * 16) ^ ((r0 & 7) << 4))) = a0;
      *(u32x4*)(Hl + r1 * 1536 + ((c1 * 16) ^ ((r1 & 7) << 4))) = a1;
    }
    __syncthreads();                           // B2
    // (D) hp MFMA; r/z waves seeded with acc_x (merged xr+hr, xz+hz)
    f32x4 acc;
    if (w < 4) acc = acc_x;
    else { f32x4 z = {0.f, 0.f, 0.f, 0.f}; acc = z; }
#pragma unroll
    for (int kt = 0; kt < 24; ++kt) {
      bf16x8 bfr = *(const bf16x8*)(Hl + (c & 7) * 1536 +
                    ((kt * 64 + kg * 16) ^ ((c & 7) << 4)));
      acc = __builtin_amdgcn_mfma_f32_16x16x32_bf16(afr[kt], bfr, acc, 0, 0, 0);
    }
    if (c < 8) {
      *(f32x4*)&hp[c][w * 16 + kg * 4] = acc;
      if (w >= 4)                              // n waves: xn kept separate
        *(f32x4*)&hp[c][96 + (w - 4) * 16 + kg * 4] = acc_x;
    }
    __syncthreads();                           // B3
    // (E2) acc_x(k+1) MFMA from Xl[(k+1)&1] (fills former idle gap)
    {
      const char* xb = Xl + ((k + 1) & 1) * 12288;
      f32x4 z = {0.f, 0.f, 0.f, 0.f}; acc_x = z;
#pragma unroll
      for (int kt = 0; kt < 24; ++kt) {
        bf16x8 bfr = *(const bf16x8*)(xb + (c & 7) * 1536 +
                      ((kt * 64 + kg * 16) ^ ((c & 7) << 4)));
        acc_x = __builtin_amdgcn_mfma_f32_16x16x32_bf16(air[kt], bfr, acc_x, 0, 0, 0);
      }
    }
    // (E) gates; h lives in gate-thread registers
    if (t < 256) {
      float r  = 1.f / (1.f + __expf(-(hp[s][d] + b_r)));
      float z  = 1.f / (1.f + __expf(-(hp[s][32 + d] + b_z)));
      float nn = tanhf(hp[s][96 + d] + b_in + r * (hp[s][64 + d] + b_hn));
      float hn = (1.f - z) * nn + z * h;
      if (k < cnt_s) h = hn;
      hstage[(s << 5) | d] = f2bf(h);
    }
    __syncthreads();                           // B4
    // (F) publish h slice (v5 verbatim) + vmcnt + flag
    if (t < 32) {
      u32x4 q = *(const u32x4*)((const char*)hstage + (t >> 2) * 64 + (t & 3) * 16);
      store_h16(Hb + (size_t)((k + 1) & 1) * HXE + (size_t)(g * 8 + (t >> 2)) * ND
                + d0 + (t & 3) * 8, q);
    }
    waitcnt_vm0();
    if (t == 0) store_flag(&FG[m * 16], k + 2);
  }

  // classifier partials over my 32 dims
  if (t < 256) {
    float p0 = h * wcls[d0 + d];
    float p1 = h * wcls[ND + d0 + d];
#pragma unroll
    for (int off = 16; off; off >>= 1) {
      p0 += __shfl_xor(p0, off);
      p1 += __shfl_xor(p1, off);
    }
    if (d == 0) {
      partial[(size_t)(m * 64 + sg) * 2]     = p0;
      partial[(size_t)(m * 64 + sg) * 2 + 1] = p1;
    }
  }
}

// ---------------- finalize: sum partials + softmax ----------------
__global__ void finalize(const float* __restrict__ partial,
                         const float* __restrict__ bcls,
                         float* __restrict__ out) {
  int s = threadIdx.x;                         // 64
  float l0 = bcls[0], l1 = bcls[1];
  for (int m = 0; m < NM; ++m) {
    l0 += partial[(size_t)(m * 64 + s) * 2];
    l1 += partial[(size_t)(m * 64 + s) * 2 + 1];
  }
  float mx = fmaxf(l0, l1);
  float e0 = __expf(l0 - mx), e1 = __expf(l1 - mx);
  float inv = 1.f / (e0 + e1);
  out[2 * s]     = e0 * inv;
  out[2 * s + 1] = e1 * inv;
}

extern "C" void kernel_launch(void* const* d_in, const int* in_sizes, int n_in,
                              void* d_out, int out_size, void* d_ws, size_t ws_size,
                              hipStream_t stream) {
  const float* seq  = (const float*)d_in[0];
  const int*   sot  = (const int*)d_in[1];
  const float* Wih  = (const float*)d_in[2];
  const float* Whh  = (const float*)d_in[3];
  const float* bih  = (const float*)d_in[4];
  const float* bhh  = (const float*)d_in[5];
  const float* Wcls = (const float*)d_in[6];
  const float* bcls = (const float*)d_in[7];
  float* out = (float*)d_out;

  char* ws = (char*)d_ws;
  int*            pos  = (int*)(ws);                              // 131,072
  int*            ctrl = (int*)(ws + 131072);                     // +512
  int*            flg  = (int*)(ws + 131584);                     // +12,288
  unsigned short* Hb   = (unsigned short*)(ws + 143872);          // +196,608
  float*          part = (float*)(ws + 340480);                   // +12,288

  hipMemsetAsync(ctrl, 0, 512 + 12288, stream);   // ctrl + flags
  compact_pos<<<NB, NS, 0, stream>>>(sot, pos, ctrl);
  rnn_gang<<<192, 384, 0, stream>>>(seq, pos, ctrl, Whh, Wih, bhh, bih,
                                    flg, Hb, Wcls, part);
  finalize<<<1, 64, 0, stream>>>(part, bcls, out);
}

// Round 12
// 1257.931 us; speedup vs baseline: 1.5864x; 1.2464x over previous
//
#include <hip/hip_runtime.h>
#include <hip/hip_bf16.h>

// RSmatching: masked-gather GRU + 2-class softmax head.
// v11 = v5's rnn protocol VERBATIM (lesson bank L1-L4) + concurrent xg
//       production on spare CUs (one fused dispatch, roles split by blockIdx):
//  - blocks 0..191: 8 gangs x 24 members. Member m: h-dims [32m,32m+32),
//    96 W_hh rows as VGPR fragments (converted fp32->bf16 in prologue).
//    Per step: wave-0 poll (24 flags + lane24 xgdone) -> bulk H stage +
//    cooperative xg stage (threads 0-95, one 16B sc0 sc1 load each, one
//    shared vmcnt) -> MFMA -> gates (x from LDS xbuf) -> gathered publish
//    -> vmcnt -> flag. 4 barriers/step, identical to v5.
//  - blocks 192..255: 64 gemm workers on otherwise-idle CUs. Dynamic tile
//    claim (ctrl[65] atomic) in ascending-k order; BM=128 x BN=192 bf16
//    MFMA tiles; LDS-transpose epilogue -> coalesced 16B sc0 sc1 stores;
//    vmcnt; atomicAdd(xgdone[chunk]). 12 tiles per 128-row chunk.
//  - xg flows gemm->LLC->rnn entirely via sc0 sc1 (no inter-dispatch flush
//    needed); readiness certified by xgdone before any read.
//  - watchdogs on every poll => guaranteed termination.

#define NB 64
#define NS 512
#define ND 768
#define TD 2304
#define NM 24
#define HXE 49152          // bf16 elems per parity of Hb
#define BNW 192
#define NT 12              // tiles per 128-row chunk (2304/192)
#define RNNB 192
#define WRK 64

typedef __attribute__((ext_vector_type(4))) float f32x4;
typedef __attribute__((ext_vector_type(8))) short bf16x8;
typedef __attribute__((ext_vector_type(4))) unsigned int u32x4;

__device__ inline unsigned short f2bf(float f) {
  union { float f; unsigned u; } a; a.f = f;
  unsigned r = a.u + 0x7fff + ((a.u >> 16) & 1);
  return (unsigned short)(r >> 16);
}
__device__ inline float bf2f(unsigned short s) {
  union { unsigned u; float f; } a; a.u = ((unsigned)s) << 16;
  return a.f;
}
__device__ inline bf16x8 pack8(float4 a, float4 b) {
  bf16x8 r;
  r[0] = (short)f2bf(a.x); r[1] = (short)f2bf(a.y);
  r[2] = (short)f2bf(a.z); r[3] = (short)f2bf(a.w);
  r[4] = (short)f2bf(b.x); r[5] = (short)f2bf(b.y);
  r[6] = (short)f2bf(b.z); r[7] = (short)f2bf(b.w);
  return r;
}

// ---- device-scope (LLC-served, L1+L2 bypass) helpers (v5 verbatim) ----
__device__ inline int load_flag(const int* p) {
  int v;
  asm volatile("global_load_dword %0, %1, off sc0 sc1\n\ts_waitcnt vmcnt(0)"
               : "=v"(v) : "v"(p) : "memory");
  return v;
}
__device__ inline void store_flag(int* p, int v) {
  asm volatile("global_store_dword %0, %1, off sc0 sc1"
               :: "v"(p), "v"(v) : "memory");
}
__device__ inline void store_h16(void* p, u32x4 v) {
  asm volatile("global_store_dwordx4 %0, %1, off sc0 sc1"
               :: "v"(p), "v"(v) : "memory");
}
__device__ inline void load1_h16(const void* p, u32x4& a) {
  asm volatile("global_load_dwordx4 %0, %1, off sc0 sc1\n\t"
               "s_waitcnt vmcnt(0)"
               : "=&v"(a) : "v"(p) : "memory");
}
// xg chunk + two H chunks, ONE vmcnt (xg latency folds into H stage RT)
__device__ inline void load3_h16(const void* px, const void* p0, const void* p1,
                                 u32x4& x, u32x4& a, u32x4& b) {
  asm volatile("global_load_dwordx4 %0, %3, off sc0 sc1\n\t"
               "global_load_dwordx4 %1, %4, off sc0 sc1\n\t"
               "global_load_dwordx4 %2, %5, off sc0 sc1\n\t"
               "s_waitcnt vmcnt(0)"
               : "=&v"(x), "=&v"(a), "=&v"(b)
               : "v"(px), "v"(p0), "v"(p1) : "memory");
}
__device__ inline void waitcnt_vm0() {
  asm volatile("s_waitcnt vmcnt(0)" ::: "memory");
}

// ---------------- fp32 -> bf16 (W_ih for the gemm workers) ----------------
__global__ void cvt_f32_bf16(const float* __restrict__ in,
                             unsigned short* __restrict__ out, int n) {
  int i = (blockIdx.x * blockDim.x + threadIdx.x) * 4;
  int stride = gridDim.x * blockDim.x * 4;
  for (; i < n; i += stride) {
    float4 v = *(const float4*)(in + i);
    ushort4 o;
    o.x = f2bf(v.x); o.y = f2bf(v.y); o.z = f2bf(v.z); o.w = f2bf(v.w);
    *(ushort4*)(out + i) = o;
  }
}

// ---------------- compact selected positions ----------------
// ctrl[0..63]=cnt, ctrl[64]=cntmax, ctrl[65]=tile counter
__global__ void compact_pos(const int* __restrict__ sot,
                            int* __restrict__ pos, int* __restrict__ ctrl) {
  int b = blockIdx.x, t = threadIdx.x;          // 512 threads
  int m = (sot[b * NS + t] != 0) ? 1 : 0;
  unsigned long long ball = __ballot(m);
  int wid = t >> 6, lane = t & 63;
  __shared__ int wcnt[8];
  int prefix = __popcll(ball & ((1ull << lane) - 1ull));
  if (lane == 63) wcnt[wid] = __popcll(ball);
  __syncthreads();
  int base = 0;
  for (int w = 0; w < wid; ++w) base += wcnt[w];
  if (m) pos[b * NS + base + prefix] = t;
  if (t == 511) {
    int total = base + wcnt[7];
    ctrl[b] = total;
    atomicMax(&ctrl[64], total);
  }
}

// ==================== fused kernel: rnn gangs + gemm workers ====================
__global__ __launch_bounds__(384) void rnn_fused(
    const float* __restrict__ seq,             // fp32 [64][512][768]
    const int* __restrict__ pos,
    int* __restrict__ ctrl,
    const unsigned short* __restrict__ wihb,   // W_ih bf16 [2304][768]
    const float* __restrict__ bih,
    const float* __restrict__ whh,             // W_hh fp32 [2304][768]
    const float* __restrict__ bhh,
    unsigned short* __restrict__ xg,           // bf16 [512*64][2304] (LLC)
    int* __restrict__ xgdone,                  // [256] chunk counters
    int* __restrict__ flags,                   // [8][24] x16 ints
    unsigned short* __restrict__ Hb,           // bf16 [2][64][768]
    const float* __restrict__ wcls,
    float* __restrict__ partial) {             // fp32 [24][64][2]
  __shared__ __align__(16) char BIG[49152];
  const int bid = blockIdx.x;
  const int t = threadIdx.x;
  const int w = t >> 6, lane = t & 63;
  const int cntmax = ctrl[64];
  const int nchunks = (cntmax + 1) >> 1;

  if (bid >= RNNB) {
    // ---------------- gemm worker role (64 blocks, own CUs) ----------------
    unsigned short* lA = (unsigned short*)BIG;            // 128x64 -> 16384
    unsigned short* lB = (unsigned short*)(BIG + 16384);  // 192x64 -> 24576
    int* smi = (int*)(BIG + 49136);
    const int total = nchunks * NT;
    const int wr = w & 1, wc = w >> 1;         // 2x3 wave grid (64x64 tiles)

    for (;;) {
      __syncthreads();                         // protect BIG reuse
      if (t == 0) smi[0] = atomicAdd(&ctrl[65], 1);
      __syncthreads();
      const int T = smi[0];
      if (T >= total) break;
      const int kchunk = T / NT, ntile = T - kchunk * NT;
      const int m0 = kchunk << 7, n0 = ntile * BNW;

      f32x4 acc[4][4];
#pragma unroll
      for (int i = 0; i < 4; ++i)
#pragma unroll
        for (int j = 0; j < 4; ++j) { f32x4 z = {0.f,0.f,0.f,0.f}; acc[i][j] = z; }

      for (int kt = 0; kt < 12; ++kt) {        // K = 768
        __syncthreads();
        for (int idx = t; idx < 1024; idx += 384) {    // stage A (gather+cvt)
          int r = idx >> 3, ch = idx & 7;
          int gm = m0 + r, ks = gm >> 6, ss = gm & 63;
          float4 v0 = {0,0,0,0}, v1 = {0,0,0,0};
          if (ks < ctrl[ss]) {
            int tp = pos[ss * NS + ks];
            const float* src = seq + ((size_t)ss * NS + tp) * ND + kt * 64 + ch * 8;
            v0 = *(const float4*)src;
            v1 = *(const float4*)(src + 4);
          }
          uint4 o;
          o.x = (unsigned)f2bf(v0.x) | ((unsigned)f2bf(v0.y) << 16);
          o.y = (unsigned)f2bf(v0.z) | ((unsigned)f2bf(v0.w) << 16);
          o.z = (unsigned)f2bf(v1.x) | ((unsigned)f2bf(v1.y) << 16);
          o.w = (unsigned)f2bf(v1.z) | ((unsigned)f2bf(v1.w) << 16);
          *(uint4*)((char*)lA + r * 128 + ((ch * 16) ^ ((r & 7) << 4))) = o;
        }
        for (int idx = t; idx < 1536; idx += 384) {    // stage B (bf16)
          int r = idx >> 3, ch = idx & 7;
          uint4 v = *(const uint4*)(wihb + (size_t)(n0 + r) * ND + kt * 64 + ch * 8);
          *(uint4*)((char*)lB + r * 128 + ((ch * 16) ^ ((r & 7) << 4))) = v;
        }
        __syncthreads();
#pragma unroll
        for (int kk = 0; kk < 2; ++kk) {
          const int kb = kk * 64 + (lane >> 4) * 16;
          bf16x8 af[4], bfr[4];
#pragma unroll
          for (int i = 0; i < 4; ++i) {
            int rowA = wr * 64 + i * 16 + (lane & 15);
            af[i] = *(const bf16x8*)((const char*)lA + rowA * 128 + (kb ^ ((rowA & 7) << 4)));
            int rowB = wc * 64 + i * 16 + (lane & 15);
            bfr[i] = *(const bf16x8*)((const char*)lB + rowB * 128 + (kb ^ ((rowB & 7) << 4)));
          }
#pragma unroll
          for (int mi = 0; mi < 4; ++mi)
#pragma unroll
            for (int ni = 0; ni < 4; ++ni)
              acc[mi][ni] = __builtin_amdgcn_mfma_f32_16x16x32_bf16(
                  af[mi], bfr[ni], acc[mi][ni], 0, 0, 0);
        }
      }
      // epilogue: LDS transpose -> coalesced 16B sc0 sc1 stores
      __syncthreads();
      unsigned short* tl = (unsigned short*)BIG;        // 128 x 192
#pragma unroll
      for (int ni = 0; ni < 4; ++ni) {
        int col = wc * 64 + ni * 16 + (lane & 15);
        float bv = bih[n0 + col];
#pragma unroll
        for (int mi = 0; mi < 4; ++mi)
#pragma unroll
          for (int j = 0; j < 4; ++j) {
            int row = wr * 64 + mi * 16 + (lane >> 4) * 4 + j;
            tl[row * BNW + col] = f2bf(acc[mi][ni][j] + bv);
          }
      }
      __syncthreads();
#pragma unroll
      for (int i = 0; i < 8; ++i) {            // 3072 x 16B chunks
        int cc = t + i * 384;
        int row = cc / 24, cb = cc - row * 24;
        u32x4 q = *(const u32x4*)((const char*)tl + row * 384 + cb * 16);
        store_h16(xg + (size_t)(m0 + row) * TD + n0 + cb * 8, q);
      }
      waitcnt_vm0();
      __syncthreads();
      if (t == 0) atomicAdd(&xgdone[kchunk], 1);
    }
    return;
  }

  // ---------------- rnn gang role (v5 loop + LDS xbuf for xg) ----------------
  const int g  = bid & 7;                      // gang
  const int m  = bid >> 3;                     // member 0..23
  const int d0 = m * 32;
  const int c  = lane & 15;
  const int kg = lane >> 4;

  char* Hl = BIG;                                        // 12288, swizzled
  unsigned short* xbuf = (unsigned short*)(BIG + 12288); // 3072: [2][8][3][32]
  float* hp = (float*)(BIG + 15360);                     // [8][136] padded
  unsigned short* hstage = (unsigned short*)(BIG + 19712); // 512

  // W_hh fragments -> registers (96 VGPR), fp32->bf16 inline
  const int lr = w * 16 + c;                   // local gate row 0..95
  const int grow = (lr >> 5) * ND + d0 + (lr & 31);
  bf16x8 afr[24];
#pragma unroll
  for (int kt = 0; kt < 24; ++kt) {
    const float* s1 = whh + (size_t)grow * ND + kt * 32 + kg * 8;
    afr[kt] = pack8(*(const float4*)s1, *(const float4*)(s1 + 4));
  }

  const int s  = (t >> 5) & 7;                 // gate-thread sample (t<256)
  const int d  = t & 31;                       // gate-thread dim
  const int sg = g * 8 + s;
  float br = 0.f, bz = 0.f, bn = 0.f, h = 0.f;
  int cnt_s = 0;
  if (t < 256) {
    br = bhh[d0 + d]; bz = bhh[ND + d0 + d]; bn = bhh[2 * ND + d0 + d];
    cnt_s = ctrl[sg];
  }
  int Kg = 0;
  for (int i = 0; i < 8; ++i) Kg = max(Kg, ctrl[g * 8 + i]);
  int* FG = flags + g * NM * 16;
  const int pm = lane < NM ? lane : (lane < 2 * NM ? lane - NM : lane - 2 * NM);

  // xg cooperative-stage geometry: thread t<96 owns one 16B chunk
  const int sx = t / 12;                       // sample 0..7
  const int qx = (t - sx * 12) >> 2;           // gate 0..2
  const int cx = t & 3;                        // 8-elem chunk 0..3
  const int xoff = (sx * 3 + qx) * 64 + cx * 16;   // byte off within parity

  // zero both parities of my H slice, publish flag=1 (v5 verbatim)
  if (t < 32) {
    u32x4 z = {0u, 0u, 0u, 0u};
    store_h16(Hb + ((size_t)(g * 8 + (t >> 2))) * ND + d0 + (t & 3) * 8, z);
    store_h16(Hb + ((size_t)(64 + g * 8 + (t >> 2))) * ND + d0 + (t & 3) * 8, z);
  }
  waitcnt_vm0();
  __syncthreads();
  if (t == 0) store_flag(&FG[m * 16], 1);

  // prologue: wait chunk 0, stage xbuf[0]
  if (w == 0 && lane == 0) {
    int spins = 0;
    while (load_flag(&xgdone[0]) < NT) { if (++spins > (1 << 20)) break; }
  }
  __syncthreads();
  if (t < 96) {
    u32x4 xq;
    load1_h16(xg + ((size_t)sg - s + sx) * TD + qx * ND + d0 + cx * 8, xq);
    *(u32x4*)((char*)xbuf + xoff) = xq;
  }
  __syncthreads();

  int dead = 0;
  for (int k = 0; k < Kg; ++k) {
    const int kn = (k + 1 < Kg) ? k + 1 : k;
    // (B) poll: 24 member flags + lane 24 checks xg chunk for step kn
    if (w == 0 && !dead) {
      int cidx = kn >> 1; if (cidx >= nchunks) cidx = nchunks - 1;
      const int* fp = (lane < NM) ? &FG[pm * 16]
                    : (lane == NM) ? &xgdone[cidx] : &FG[0];
      const unsigned tk = (unsigned)(k + 1);
      int spins = 0;
      while (true) {
        int v = load_flag(fp);
        int ok = (lane < NM) ? ((unsigned)v >= tk)
               : (lane == NM) ? (v >= NT) : 1;
        if (__all(ok)) break;
        if (++spins > (1 << 20)) { dead = 1; break; }
      }
    }
    __syncthreads();                           // B1
    // (C) stage H(k) + xg(k+1): 3 loads, ONE vmcnt (v5 stage + xbuf)
    {
      const unsigned short* hsrc = Hb + ((size_t)(k & 1) * 64 + g * 8) * ND;
      int i1 = t + 384;
      int r0 = t / 96, c0 = t - r0 * 96;
      int r1 = i1 / 96, c1 = i1 - r1 * 96;
      const unsigned short* xs = (t < 96)
          ? xg + ((size_t)kn * 64 + g * 8 + sx) * TD + qx * ND + d0 + cx * 8
          : (const unsigned short*)xg;         // clamped safe addr
      u32x4 xq, a0, a1;
      load3_h16(xs, hsrc + r0 * ND + c0 * 8, hsrc + r1 * ND + c1 * 8, xq, a0, a1);
      *(u32x4*)(Hl + r0 * 1536 + ((c0 * 16) ^ ((r0 & 7) << 4))) = a0;
      *(u32x4*)(Hl + r1 * 1536 + ((c1 * 16) ^ ((r1 & 7) << 4))) = a1;
      if (t < 96 && k + 1 < Kg)
        *(u32x4*)((char*)xbuf + ((k + 1) & 1) * 1536 + xoff) = xq;
    }
    __syncthreads();                           // B2
    // (D) MFMA: hp[96 rows][8 samples] for my tile
    f32x4 acc = {0.f, 0.f, 0.f, 0.f};
#pragma unroll
    for (int kt = 0; kt < 24; ++kt) {
      bf16x8 bfr = *(const bf16x8*)(Hl + (c & 7) * 1536 +
                    ((kt * 64 + kg * 16) ^ ((c & 7) << 4)));
      acc = __builtin_amdgcn_mfma_f32_16x16x32_bf16(afr[kt], bfr, acc, 0, 0, 0);
    }
    if (c < 8) *(f32x4*)&hp[(size_t)c * 136 + w * 16 + kg * 4] = acc;
    __syncthreads();                           // B3
    // (E) gates; x from LDS xbuf; h lives in gate-thread registers
    if (t < 256) {
      const unsigned short* xb = xbuf + (k & 1) * 768;   // ushort units
      float xr = bf2f(xb[(s * 3 + 0) * 32 + d]);
      float xz = bf2f(xb[(s * 3 + 1) * 32 + d]);
      float xn = bf2f(xb[(s * 3 + 2) * 32 + d]);
      float ar = hp[(size_t)s * 136 + d]      + br;
      float az = hp[(size_t)s * 136 + 32 + d] + bz;
      float an = hp[(size_t)s * 136 + 64 + d] + bn;
      float r  = 1.f / (1.f + __expf(-(xr + ar)));
      float z  = 1.f / (1.f + __expf(-(xz + az)));
      float nn = tanhf(xn + r * an);
      float hn = (1.f - z) * nn + z * h;
      if (k < cnt_s) h = hn;
      hstage[(s << 5) | d] = f2bf(h);
    }
    __syncthreads();                           // B4
    // (F) publish h slice (v5 verbatim) + vmcnt + flag
    if (t < 32) {
      u32x4 q = *(const u32x4*)((const char*)hstage + (t >> 2) * 64 + (t & 3) * 16);
      store_h16(Hb + (size_t)((k + 1) & 1) * HXE + (size_t)(g * 8 + (t >> 2)) * ND
                + d0 + (t & 3) * 8, q);
    }
    waitcnt_vm0();
    if (t == 0) store_flag(&FG[m * 16], k + 2);
  }

  // classifier partials over my 32 dims
  if (t < 256) {
    float p0 = h * wcls[d0 + d];
    float p1 = h * wcls[ND + d0 + d];
#pragma unroll
    for (int off = 16; off; off >>= 1) {
      p0 += __shfl_xor(p0, off);
      p1 += __shfl_xor(p1, off);
    }
    if (d == 0) {
      partial[(size_t)(m * 64 + sg) * 2]     = p0;
      partial[(size_t)(m * 64 + sg) * 2 + 1] = p1;
    }
  }
}

// ---------------- finalize: sum partials + softmax ----------------
__global__ void finalize(const float* __restrict__ partial,
                         const float* __restrict__ bcls,
                         float* __restrict__ out) {
  int s = threadIdx.x;                         // 64
  float l0 = bcls[0], l1 = bcls[1];
  for (int m = 0; m < NM; ++m) {
    l0 += partial[(size_t)(m * 64 + s) * 2];
    l1 += partial[(size_t)(m * 64 + s) * 2 + 1];
  }
  float mx = fmaxf(l0, l1);
  float e0 = __expf(l0 - mx), e1 = __expf(l1 - mx);
  float inv = 1.f / (e0 + e1);
  out[2 * s]     = e0 * inv;
  out[2 * s + 1] = e1 * inv;
}

extern "C" void kernel_launch(void* const* d_in, const int* in_sizes, int n_in,
                              void* d_out, int out_size, void* d_ws, size_t ws_size,
                              hipStream_t stream) {
  const float* seq  = (const float*)d_in[0];
  const int*   sot  = (const int*)d_in[1];
  const float* Wih  = (const float*)d_in[2];
  const float* Whh  = (const float*)d_in[3];
  const float* bih  = (const float*)d_in[4];
  const float* bhh  = (const float*)d_in[5];
  const float* Wcls = (const float*)d_in[6];
  const float* bcls = (const float*)d_in[7];
  float* out = (float*)d_out;

  char* ws = (char*)d_ws;
  unsigned short* xg   = (unsigned short*)(ws);                   // 150,994,944
  unsigned short* wihb = (unsigned short*)(ws + 150994944);       // +3,538,944
  int*            pos  = (int*)(ws + 154533888);                  // +131,072
  int*            ctrl = (int*)(ws + 154664960);                  // +512
  int*            flg  = (int*)(ws + 154665472);                  // +12,288
  int*            xgd  = (int*)(ws + 154677760);                  // +1,024
  unsigned short* Hb   = (unsigned short*)(ws + 154678784);       // +196,608
  float*          part = (float*)(ws + 154875392);                // +12,288

  cvt_f32_bf16<<<1728, 256, 0, stream>>>(Wih, wihb, TD * ND);
  hipMemsetAsync(ctrl, 0, 512 + 12288 + 1024, stream);  // ctrl+flags+xgdone
  compact_pos<<<NB, NS, 0, stream>>>(sot, pos, ctrl);
  rnn_fused<<<RNNB + WRK, 384, 0, stream>>>(
      seq, pos, ctrl, wihb, bih, Whh, bhh, xg, xgd, flg, Hb, Wcls, part);
  finalize<<<1, 64, 0, stream>>>(part, bcls, out);
}

// Round 13
// 972.188 us; speedup vs baseline: 2.0527x; 1.2939x over previous
//
#include <hip/hip_runtime.h>
#include <hip/hip_bf16.h>

// RSmatching: masked-gather GRU + 2-class softmax head.
// v12 = v5 (best measured: 975 us total, rnn 730 us) restored VERBATIM in
//       all hot paths, with the two W-conversion dispatches merged into one.
// Structure (proven across rounds 6-11; lessons L1-L4):
//  - 8 gangs x 24 members (192 WGs x 384 thr), gang = blockIdx&7.
//  - member m owns h-dims [32m,32m+32): 96 W_hh rows in VGPR fragments.
//  - per step: wave-0-only poll of 24 padded flags (sc0 sc1 LLC loads) ->
//    bulk 16B H stage -> swizzled LDS -> 24 MFMA/wave -> gates ->
//    gathered publish (32x16B sc0 sc1) -> vmcnt(0) -> flag store.
//    NO fences; 4 barriers/step. Protocol frozen (L1).
//  - xg on the CACHED path, produced by a separate gemm dispatch (L2/L4).
//  - watchdog on the poll => guaranteed termination.
// Structural ceiling: ~282 sequential steps x ~2.5 us LLC-RT chain + ~200 us
// GEMM head. Six protocol/fusion variants (v6-v11) all regressed; this is
// the measured optimum.

#define NB 64
#define NS 512
#define ND 768
#define TD 2304
#define NM 24

typedef __attribute__((ext_vector_type(4))) float f32x4;
typedef __attribute__((ext_vector_type(8))) short bf16x8;
typedef __attribute__((ext_vector_type(4))) unsigned int u32x4;

__device__ inline unsigned short f2bf(float f) {
  union { float f; unsigned u; } a; a.f = f;
  unsigned r = a.u + 0x7fff + ((a.u >> 16) & 1);
  return (unsigned short)(r >> 16);
}
__device__ inline float bf2f(unsigned short s) {
  union { unsigned u; float f; } a; a.u = ((unsigned)s) << 16;
  return a.f;
}

// ---- device-scope (LLC-served, L1+L2 bypass) access helpers ----
__device__ inline int load_flag(const int* p) {
  int v;
  asm volatile("global_load_dword %0, %1, off sc0 sc1\n\ts_waitcnt vmcnt(0)"
               : "=v"(v) : "v"(p) : "memory");
  return v;
}
__device__ inline void store_flag(int* p, int v) {
  asm volatile("global_store_dword %0, %1, off sc0 sc1"
               :: "v"(p), "v"(v) : "memory");
}
__device__ inline void store_h16(void* p, u32x4 v) {
  asm volatile("global_store_dwordx4 %0, %1, off sc0 sc1"
               :: "v"(p), "v"(v) : "memory");
}
__device__ inline void load2_h16(const void* p0, const void* p1,
                                 u32x4& a, u32x4& b) {
  asm volatile("global_load_dwordx4 %0, %2, off sc0 sc1\n\t"
               "global_load_dwordx4 %1, %3, off sc0 sc1\n\t"
               "s_waitcnt vmcnt(0)"
               : "=&v"(a), "=&v"(b) : "v"(p0), "v"(p1) : "memory");
}
__device__ inline void waitcnt_vm0() {
  asm volatile("s_waitcnt vmcnt(0)" ::: "memory");
}

// ---------------- fp32 -> bf16 (both W matrices, one dispatch) ------------
__global__ void cvt_w2(const float* __restrict__ inA,
                       unsigned short* __restrict__ outA,
                       const float* __restrict__ inB,
                       unsigned short* __restrict__ outB, int n) {
  int i = (blockIdx.x * blockDim.x + threadIdx.x) * 4;
  int stride = gridDim.x * blockDim.x * 4;
  for (; i < n; i += stride) {
    float4 va = *(const float4*)(inA + i);
    ushort4 oa;
    oa.x = f2bf(va.x); oa.y = f2bf(va.y); oa.z = f2bf(va.z); oa.w = f2bf(va.w);
    *(ushort4*)(outA + i) = oa;
    float4 vb = *(const float4*)(inB + i);
    ushort4 ob;
    ob.x = f2bf(vb.x); ob.y = f2bf(vb.y); ob.z = f2bf(vb.z); ob.w = f2bf(vb.w);
    *(ushort4*)(outB + i) = ob;
  }
}

// ---------------- compact selected positions ----------------
// ctrl[0..63]=cnt, ctrl[64]=cntmax
__global__ void compact_pos(const int* __restrict__ sot,
                            int* __restrict__ pos, int* __restrict__ ctrl) {
  int b = blockIdx.x, t = threadIdx.x;          // 512 threads
  int m = (sot[b * NS + t] != 0) ? 1 : 0;
  unsigned long long ball = __ballot(m);
  int wid = t >> 6, lane = t & 63;
  __shared__ int wcnt[8];
  int prefix = __popcll(ball & ((1ull << lane) - 1ull));
  if (lane == 63) wcnt[wid] = __popcll(ball);
  __syncthreads();
  int base = 0;
  for (int w = 0; w < wid; ++w) base += wcnt[w];
  if (m) pos[b * NS + base + prefix] = t;
  if (t == 511) {
    int total = base + wcnt[7];
    ctrl[b] = total;
    atomicMax(&ctrl[64], total);
  }
}

// ---------------- xg GEMM: gathered rows -> x-projection ----------------
#define BM 128
#define BN 256
__global__ __launch_bounds__(256) void gemm_xg(
    const float* __restrict__ seq,           // fp32 [64][512][768]
    const int* __restrict__ pos,
    const int* __restrict__ ctrl,
    const unsigned short* __restrict__ Bg,   // W_ih bf16 [2304][768]
    const float* __restrict__ bias,          // b_ih fp32
    unsigned short* __restrict__ C) {        // xg bf16 [32768][2304]
  const int cntmax = ctrl[64];
  const int m0 = blockIdx.x * BM;
  if (m0 >= cntmax * 64) return;
  const int n0 = blockIdx.y * BN;
  __shared__ unsigned short lA[BM * 64];
  __shared__ unsigned short lB[BN * 64];
  const int tid = threadIdx.x;
  const int wid = tid >> 6, lane = tid & 63;
  const int wm = (wid & 1) * 64, wn = (wid >> 1) * 128;

  f32x4 acc[4][8];
#pragma unroll
  for (int i = 0; i < 4; ++i)
#pragma unroll
    for (int j = 0; j < 8; ++j) { f32x4 z = {0.f,0.f,0.f,0.f}; acc[i][j] = z; }

  for (int kt = 0; kt < 12; ++kt) {          // K = 768 = 12*64
    __syncthreads();
#pragma unroll
    for (int c = 0; c < 4; ++c) {
      int idx = c * 256 + tid;
      int r = idx >> 3, ch = idx & 7;
      int gm = m0 + r, ks = gm >> 6, ss = gm & 63;
      float4 v0 = {0,0,0,0}, v1 = {0,0,0,0};
      if (ks < ctrl[ss]) {
        int t = pos[ss * NS + ks];
        const float* src = seq + ((size_t)ss * NS + t) * ND + kt * 64 + ch * 8;
        v0 = *(const float4*)src;
        v1 = *(const float4*)(src + 4);
      }
      uint4 o;
      o.x = f2bf(v0.x) | ((unsigned)f2bf(v0.y) << 16);
      o.y = f2bf(v0.z) | ((unsigned)f2bf(v0.w) << 16);
      o.z = f2bf(v1.x) | ((unsigned)f2bf(v1.y) << 16);
      o.w = f2bf(v1.z) | ((unsigned)f2bf(v1.w) << 16);
      *(uint4*)((char*)lA + r * 128 + ((ch * 16) ^ ((r & 7) << 4))) = o;
    }
#pragma unroll
    for (int c = 0; c < 8; ++c) {
      int idx = c * 256 + tid;
      int r = idx >> 3, ch = idx & 7;
      uint4 v = *(const uint4*)(Bg + (size_t)(n0 + r) * ND + kt * 64 + ch * 8);
      *(uint4*)((char*)lB + r * 128 + ((ch * 16) ^ ((r & 7) << 4))) = v;
    }
    __syncthreads();
#pragma unroll
    for (int kk = 0; kk < 2; ++kk) {
      bf16x8 af[4], bfr[8];
      int kb = kk * 64 + (lane >> 4) * 16;
#pragma unroll
      for (int i = 0; i < 4; ++i) {
        int rowA = wm + i * 16 + (lane & 15);
        af[i] = *(const bf16x8*)((const char*)lA + rowA * 128 + (kb ^ ((rowA & 7) << 4)));
      }
#pragma unroll
      for (int i = 0; i < 8; ++i) {
        int rowB = wn + i * 16 + (lane & 15);
        bfr[i] = *(const bf16x8*)((const char*)lB + rowB * 128 + (kb ^ ((rowB & 7) << 4)));
      }
#pragma unroll
      for (int mi = 0; mi < 4; ++mi)
#pragma unroll
        for (int ni = 0; ni < 8; ++ni)
          acc[mi][ni] = __builtin_amdgcn_mfma_f32_16x16x32_bf16(
              af[mi], bfr[ni], acc[mi][ni], 0, 0, 0);
    }
  }
#pragma unroll
  for (int mi = 0; mi < 4; ++mi)
#pragma unroll
    for (int ni = 0; ni < 8; ++ni) {
      int col = n0 + wn + ni * 16 + (lane & 15);
      float bv = bias[col];
#pragma unroll
      for (int j = 0; j < 4; ++j) {
        int row = m0 + wm + mi * 16 + (lane >> 4) * 4 + j;
        C[(size_t)row * TD + col] = f2bf(acc[mi][ni][j] + bv);
      }
    }
}

// ---------------- gang RNN (LLC-served sync, static gangs) ----------------
__global__ __launch_bounds__(384) void rnn_gang(
    const unsigned short* __restrict__ xg,     // bf16 [512*64][2304]
    const unsigned short* __restrict__ whhb,   // bf16 [2304][768]
    const float* __restrict__ bhh,
    const int* __restrict__ ctrl,
    int* __restrict__ flags,                   // [8][24] padded x16 ints
    unsigned short* __restrict__ Hb,           // bf16 [2][64][768]
    const float* __restrict__ wcls,            // fp32 [2][768]
    float* __restrict__ partial) {             // fp32 [24][64][2]
  const int g  = blockIdx.x & 7;               // gang
  const int m  = blockIdx.x >> 3;              // member 0..23
  const int d0 = m * 32;
  const int t  = threadIdx.x;
  const int w  = t >> 6;
  const int lane = t & 63;
  const int c  = lane & 15;
  const int kg = lane >> 4;

  __shared__ __align__(16) char Hl[8 * 1536];            // 12 KB, swizzled
  __shared__ __align__(16) float hp[8][100];             // padded stride
  __shared__ __align__(16) unsigned short hstage[256];

  // my wave's M-tile W fragments -> registers (96 VGPR)
  const int lr = w * 16 + c;                   // local gate row 0..95
  const int grow = (lr >> 5) * ND + d0 + (lr & 31);
  bf16x8 afr[24];
#pragma unroll
  for (int kt = 0; kt < 24; ++kt)
    afr[kt] = *(const bf16x8*)(whhb + (size_t)grow * ND + kt * 32 + kg * 8);

  const int s  = (t >> 5) & 7;                 // gate-thread sample (t<256)
  const int d  = t & 31;                       // gate-thread dim
  const int sg = g * 8 + s;
  float br = 0.f, bz = 0.f, bn = 0.f, h = 0.f;
  int cnt_s = 0;
  if (t < 256) {
    br = bhh[d0 + d]; bz = bhh[ND + d0 + d]; bn = bhh[2 * ND + d0 + d];
    cnt_s = ctrl[sg];
  }
  int Kg = 0;
  for (int i = 0; i < 8; ++i) Kg = max(Kg, ctrl[g * 8 + i]);
  int* FG = flags + g * NM * 16;
  const int pm = lane < NM ? lane : (lane < 2 * NM ? lane - NM : lane - 2 * NM);

  // zero both parities of my H slice (sc0 sc1), then publish flag=1
  if (t < 32) {
    u32x4 z = {0u, 0u, 0u, 0u};
    store_h16(Hb + ((size_t)(g * 8 + (t >> 2))) * ND + d0 + (t & 3) * 8, z);
    store_h16(Hb + ((size_t)(64 + g * 8 + (t >> 2))) * ND + d0 + (t & 3) * 8, z);
  }
  waitcnt_vm0();
  __syncthreads();
  if (t == 0) store_flag(&FG[m * 16], 1);

  int dead = 0;
  for (int k = 0; k < Kg; ++k) {
    // (A) xg load (plain cached; barrier-independent)
    float xr = 0.f, xz = 0.f, xn = 0.f;
    if (t < 256) {
      const unsigned short* xrow = xg + ((size_t)k * 64 + sg) * TD + d0 + d;
      xr = bf2f(xrow[0]); xz = bf2f(xrow[ND]); xn = bf2f(xrow[2 * ND]);
    }
    // (B) poll gang flags (sc0 sc1 -> LLC) with one-shot watchdog
    if (w == 0 && !dead) {
      const int* fp = &FG[pm * 16];
      int spins = 0;
      while (true) {
        int v = load_flag(fp);
        if (__all(v >= k + 1)) break;
        if (++spins > (1 << 20)) { dead = 1; break; }
      }
    }
    __syncthreads();
    // (C) stage H[8][768] -> swizzled LDS (sc0 sc1 loads)
    {
      const unsigned short* hsrc = Hb + ((size_t)(k & 1) * 64 + g * 8) * ND;
      int i1 = t + 384;
      int r0 = t / 96, c0 = t - r0 * 96;
      int r1 = i1 / 96, c1 = i1 - r1 * 96;
      u32x4 a0, a1;
      load2_h16(hsrc + r0 * ND + c0 * 8, hsrc + r1 * ND + c1 * 8, a0, a1);
      *(u32x4*)(Hl + r0 * 1536 + ((c0 * 16) ^ ((r0 & 7) << 4))) = a0;
      *(u32x4*)(Hl + r1 * 1536 + ((c1 * 16) ^ ((r1 & 7) << 4))) = a1;
    }
    __syncthreads();
    // (D) MFMA: hp[96 rows][8 samples] for my tile
    f32x4 acc = {0.f, 0.f, 0.f, 0.f};
#pragma unroll
    for (int kt = 0; kt < 24; ++kt) {
      bf16x8 bfr = *(const bf16x8*)(Hl + (c & 7) * 1536 +
                    ((kt * 64 + kg * 16) ^ ((c & 7) << 4)));
      acc = __builtin_amdgcn_mfma_f32_16x16x32_bf16(afr[kt], bfr, acc, 0, 0, 0);
    }
    if (c < 8) *(f32x4*)&hp[c][w * 16 + kg * 4] = acc;
    __syncthreads();
    // (E) gates; h lives in gate-thread registers
    if (t < 256) {
      float ar = hp[s][d]      + br;
      float az = hp[s][32 + d] + bz;
      float an = hp[s][64 + d] + bn;
      float r  = 1.f / (1.f + __expf(-(xr + ar)));
      float z  = 1.f / (1.f + __expf(-(xz + az)));
      float nn = tanhf(xn + r * an);
      float hn = (1.f - z) * nn + z * h;
      if (k < cnt_s) h = hn;
      hstage[(s << 5) | d] = f2bf(h);
    }
    __syncthreads();
    // (F) publish h slice (sc0 sc1) + vmcnt(0) + flag
    if (t < 32) {
      u32x4 q = *(const u32x4*)((const char*)hstage + (t >> 2) * 64 + (t & 3) * 16);
      store_h16(Hb + ((size_t)((k + 1) & 1) * 64 + g * 8 + (t >> 2)) * ND + d0 + (t & 3) * 8, q);
    }
    waitcnt_vm0();
    if (t == 0) store_flag(&FG[m * 16], k + 2);
  }

  // classifier partials over my 32 dims
  if (t < 256) {
    float p0 = h * wcls[d0 + d];
    float p1 = h * wcls[ND + d0 + d];
#pragma unroll
    for (int off = 16; off; off >>= 1) {
      p0 += __shfl_xor(p0, off);
      p1 += __shfl_xor(p1, off);
    }
    if (d == 0) {
      partial[(size_t)(m * 64 + sg) * 2]     = p0;
      partial[(size_t)(m * 64 + sg) * 2 + 1] = p1;
    }
  }
}

// ---------------- finalize: sum partials + softmax ----------------
__global__ void finalize(const float* __restrict__ partial,
                         const float* __restrict__ bcls,
                         float* __restrict__ out) {
  int s = threadIdx.x;                         // 64
  float l0 = bcls[0], l1 = bcls[1];
  for (int m = 0; m < NM; ++m) {
    l0 += partial[(size_t)(m * 64 + s) * 2];
    l1 += partial[(size_t)(m * 64 + s) * 2 + 1];
  }
  float mx = fmaxf(l0, l1);
  float e0 = __expf(l0 - mx), e1 = __expf(l1 - mx);
  float inv = 1.f / (e0 + e1);
  out[2 * s]     = e0 * inv;
  out[2 * s + 1] = e1 * inv;
}

extern "C" void kernel_launch(void* const* d_in, const int* in_sizes, int n_in,
                              void* d_out, int out_size, void* d_ws, size_t ws_size,
                              hipStream_t stream) {
  const float* seq  = (const float*)d_in[0];
  const int*   sot  = (const int*)d_in[1];
  const float* Wih  = (const float*)d_in[2];
  const float* Whh  = (const float*)d_in[3];
  const float* bih  = (const float*)d_in[4];
  const float* bhh  = (const float*)d_in[5];
  const float* Wcls = (const float*)d_in[6];
  const float* bcls = (const float*)d_in[7];
  float* out = (float*)d_out;

  char* ws = (char*)d_ws;
  unsigned short* xg   = (unsigned short*)(ws);                   // 150,994,944
  unsigned short* wihb = (unsigned short*)(ws + 150994944);       // +3,538,944
  unsigned short* whhb = (unsigned short*)(ws + 154533888);       // +3,538,944
  int*            pos  = (int*)(ws + 158072832);                  // +131,072
  int*            ctrl = (int*)(ws + 158203904);                  // +512
  int*            flg  = (int*)(ws + 158204416);                  // +12,288
  unsigned short* Hb   = (unsigned short*)(ws + 158216704);       // +196,608
  float*          part = (float*)(ws + 158413312);                // +12,288

  cvt_w2<<<1728, 256, 0, stream>>>(Wih, wihb, Whh, whhb, TD * ND);
  hipMemsetAsync(ctrl, 0, 512 + 12288, stream);   // ctrl + flags
  compact_pos<<<NB, NS, 0, stream>>>(sot, pos, ctrl);
  gemm_xg<<<dim3(NB * NS / BM, TD / BN), 256, 0, stream>>>(seq, pos, ctrl, wihb, bih, xg);
  rnn_gang<<<192, 384, 0, stream>>>(xg, whhb, bhh, ctrl, flg, Hb, Wcls, part);
  finalize<<<1, 64, 0, stream>>>(part, bcls, out);
}